// Round 1
// baseline (112.544 us; speedup 1.0000x reference)
//
#include <hip/hip_runtime.h>

#define MASK_HW 28
#define OUT_H 512
#define OUT_W 512
#define ROWS_PER_BLOCK 16

// One block: one instance (blockIdx.y) x 16 output rows (blockIdx.x).
// Mask staged into zero-padded LDS so boundary taps read zeros with no
// per-tap validity logic. Each thread stores float4 (coalesced).
__global__ __launch_bounds__(256) void paste_masks_kernel(
    const float* __restrict__ masks,   // [N,1,28,28]
    const float* __restrict__ boxes,   // [N,4]
    float* __restrict__ out)           // [N,1,512,512]
{
    __shared__ float sm[31][33];   // padded: mask at [1..28][1..28], zero border
    const int n   = blockIdx.y;
    const int tid = threadIdx.x;

    // zero the padded tile, then fill the interior
    for (int i = tid; i < 31 * 33; i += 256) ((float*)sm)[i] = 0.0f;
    __syncthreads();
    const float* mptr = masks + (size_t)n * (MASK_HW * MASK_HW);
    for (int i = tid; i < MASK_HW * MASK_HW; i += 256) {
        int r = i / MASK_HW;
        int c = i - r * MASK_HW;
        sm[r + 1][c + 1] = mptr[i];
    }

    const float bx0 = boxes[4 * n + 0];
    const float by0 = boxes[4 * n + 1];
    const float bx1 = boxes[4 * n + 2] + 1e-5f;
    const float by1 = boxes[4 * n + 3] + 1e-5f;
    // xs = (x + 0.5 - bx0) * sxf - 0.5  maps output px -> mask coord
    const float sxf = 28.0f / (bx1 - bx0);
    const float syf = 28.0f / (by1 - by0);
    __syncthreads();

    const int row0 = blockIdx.x * ROWS_PER_BLOCK;
    float* outn = out + (size_t)n * (OUT_H * OUT_W);

    const int chunks = ROWS_PER_BLOCK * (OUT_W / 4);   // 128 float4 per row
    for (int cid = tid; cid < chunks; cid += 256) {
        const int r   = cid >> 7;          // row within group
        const int xq  = cid & 127;         // float4 index within row
        const int row = row0 + r;

        const float ys = ((float)row + 0.5f - by0) * syf - 0.5f;
        float4 v = make_float4(0.f, 0.f, 0.f, 0.f);

        if (ys > -1.0f && ys < 28.0f) {
            const float y0f = floorf(ys);
            const int   y0i = (int)y0f;            // in [-1, 27]
            const float wy1 = ys - y0f;
            const float wy0 = 1.0f - wy1;
            const float* r0 = &sm[y0i + 1][0];
            const float* r1 = &sm[y0i + 2][0];

            const float xbase = (float)(xq * 4) + 0.5f - bx0;
            float res[4];
            #pragma unroll
            for (int j = 0; j < 4; ++j) {
                const float xs = (xbase + (float)j) * sxf - 0.5f;
                float val = 0.0f;
                if (xs > -1.0f && xs < 28.0f) {
                    const float x0f = floorf(xs);
                    const int   x0i = (int)x0f;    // in [-1, 27]
                    const float wx1 = xs - x0f;
                    const float wx0 = 1.0f - wx1;
                    const float v00 = r0[x0i + 1];
                    const float v01 = r0[x0i + 2];
                    const float v10 = r1[x0i + 1];
                    const float v11 = r1[x0i + 2];
                    val = wy0 * (wx0 * v00 + wx1 * v01) +
                          wy1 * (wx0 * v10 + wx1 * v11);
                }
                res[j] = val;
            }
            v = make_float4(res[0], res[1], res[2], res[3]);
        }
        *reinterpret_cast<float4*>(outn + (size_t)row * OUT_W + xq * 4) = v;
    }
}

extern "C" void kernel_launch(void* const* d_in, const int* in_sizes, int n_in,
                              void* d_out, int out_size, void* d_ws, size_t ws_size,
                              hipStream_t stream) {
    const float* masks = (const float*)d_in[0];   // [100,1,28,28] fp32
    const float* boxes = (const float*)d_in[1];   // [100,4] fp32
    float* out = (float*)d_out;                   // [100,1,512,512] fp32

    dim3 grid(OUT_H / ROWS_PER_BLOCK, 100);       // (32, 100)
    dim3 block(256);
    paste_masks_kernel<<<grid, block, 0, stream>>>(masks, boxes, out);
}